// Round 1
// baseline (611.074 us; speedup 1.0000x reference)
//
#include <hip/hip_runtime.h>

namespace {
constexpr int NN  = 100000;   // nodes
constexpr int NE  = 1000000;  // edges
constexpr int INF = 256;
constexpr int HF  = 64;
constexpr int OF  = 16;
}

// ---- degree / normalization ------------------------------------------------

__global__ void k_init_deg(float* __restrict__ deg) {
    int v = blockIdx.x * 256 + threadIdx.x;
    if (v < NN) deg[v] = 1.0f;   // self-loop contributes 1
}

__global__ void k_accum_deg(const int* __restrict__ dst, float* __restrict__ deg) {
    int e = blockIdx.x * 256 + threadIdx.x;
    if (e < NE) atomicAdd(&deg[dst[e]], 1.0f);
}

__global__ void k_dinv(float* __restrict__ deg) {
    int v = blockIdx.x * 256 + threadIdx.x;
    if (v < NN) deg[v] = rsqrtf(deg[v]);   // deg >= 1 always
}

// ---- GEMM1: h1 = x @ W1   [NN,256] x [256,64] ------------------------------
// 16 rows per 256-thread block; each thread computes 4 consecutive cols of 1 row.
__global__ __launch_bounds__(256) void k_gemm1(const float* __restrict__ x,
                                               const float* __restrict__ W1,
                                               float* __restrict__ h1) {
    int c   = threadIdx.x & 15;       // col group -> cols 4c..4c+3
    int r   = threadIdx.x >> 4;       // 0..15
    int row = blockIdx.x * 16 + r;
    if (row >= NN) return;
    const float* xr = x + (size_t)row * INF;
    float4 acc = {0.f, 0.f, 0.f, 0.f};
    for (int k = 0; k < INF; k += 4) {
        float4 xv = *(const float4*)(xr + k);
        float4 w0 = *(const float4*)(W1 + (size_t)(k + 0) * HF + 4 * c);
        float4 w1 = *(const float4*)(W1 + (size_t)(k + 1) * HF + 4 * c);
        float4 w2 = *(const float4*)(W1 + (size_t)(k + 2) * HF + 4 * c);
        float4 w3 = *(const float4*)(W1 + (size_t)(k + 3) * HF + 4 * c);
        acc.x += xv.x * w0.x + xv.y * w1.x + xv.z * w2.x + xv.w * w3.x;
        acc.y += xv.x * w0.y + xv.y * w1.y + xv.z * w2.y + xv.w * w3.y;
        acc.z += xv.x * w0.z + xv.y * w1.z + xv.z * w2.z + xv.w * w3.z;
        acc.w += xv.x * w0.w + xv.y * w1.w + xv.z * w2.w + xv.w * w3.w;
    }
    *(float4*)(h1 + (size_t)row * HF + 4 * c) = acc;
}

// ---- Aggregation 1: agg[d] += norm(s,d) * h1[s], 64 lanes per edge ---------
__global__ __launch_bounds__(256) void k_aggregate1(const int* __restrict__ src,
                                                    const int* __restrict__ dst,
                                                    const float* __restrict__ dinv,
                                                    const float* __restrict__ h1,
                                                    float* __restrict__ agg) {
    int idx = blockIdx.x * 256 + threadIdx.x;
    int e = idx >> 6;
    int j = idx & 63;
    if (e < NE) {
        int s = src[e], d = dst[e];
        float w = dinv[s] * dinv[d];
        atomicAdd(&agg[(size_t)d * HF + j], w * h1[(size_t)s * HF + j]);
    }
}

// ---- Finalize 1: h = relu(agg + dinv^2 * h1 + b1), in place in agg ---------
__global__ void k_finalize1(const float* __restrict__ h1,
                            const float* __restrict__ dinv,
                            const float* __restrict__ b1,
                            float* __restrict__ agg) {
    int idx = blockIdx.x * 256 + threadIdx.x;
    if (idx < NN * HF) {
        int v = idx >> 6, j = idx & 63;
        float di = dinv[v];
        float val = agg[idx] + di * di * h1[idx] + b1[j];
        agg[idx] = val > 0.f ? val : 0.f;
    }
}

// ---- GEMM2: h2 = h @ W2   [NN,64] x [64,16] --------------------------------
__global__ __launch_bounds__(256) void k_gemm2(const float* __restrict__ h,
                                               const float* __restrict__ W2,
                                               float* __restrict__ h2) {
    int j   = threadIdx.x & 15;
    int r   = threadIdx.x >> 4;
    int row = blockIdx.x * 16 + r;
    if (row >= NN) return;
    const float* hr = h + (size_t)row * HF;
    float acc = 0.f;
    for (int k = 0; k < HF; k += 4) {
        float4 hv = *(const float4*)(hr + k);
        acc += hv.x * W2[(k + 0) * OF + j];
        acc += hv.y * W2[(k + 1) * OF + j];
        acc += hv.z * W2[(k + 2) * OF + j];
        acc += hv.w * W2[(k + 3) * OF + j];
    }
    h2[(size_t)row * OF + j] = acc;
}

// ---- Aggregation 2: out[d] += norm(s,d) * h2[s], 16 lanes per edge ---------
__global__ __launch_bounds__(256) void k_aggregate2(const int* __restrict__ src,
                                                    const int* __restrict__ dst,
                                                    const float* __restrict__ dinv,
                                                    const float* __restrict__ h2,
                                                    float* __restrict__ out) {
    int idx = blockIdx.x * 256 + threadIdx.x;
    int e = idx >> 4;
    int j = idx & 15;
    if (e < NE) {
        int s = src[e], d = dst[e];
        float w = dinv[s] * dinv[d];
        atomicAdd(&out[(size_t)d * OF + j], w * h2[(size_t)s * OF + j]);
    }
}

// ---- Finalize 2: out += dinv^2 * h2 + b2 -----------------------------------
__global__ void k_finalize2(const float* __restrict__ h2,
                            const float* __restrict__ dinv,
                            const float* __restrict__ b2,
                            float* __restrict__ out) {
    int idx = blockIdx.x * 256 + threadIdx.x;
    if (idx < NN * OF) {
        int v = idx >> 4, j = idx & 15;
        float di = dinv[v];
        out[idx] = out[idx] + di * di * h2[idx] + b2[j];
    }
}

extern "C" void kernel_launch(void* const* d_in, const int* in_sizes, int n_in,
                              void* d_out, int out_size, void* d_ws, size_t ws_size,
                              hipStream_t stream) {
    const float* x   = (const float*)d_in[0];
    const int*   ei  = (const int*)d_in[1];
    const int*   src = ei;            // edge_index[0]
    const int*   dst = ei + NE;       // edge_index[1]
    const float* W1  = (const float*)d_in[2];
    const float* b1  = (const float*)d_in[3];
    const float* W2  = (const float*)d_in[4];
    const float* b2  = (const float*)d_in[5];
    float* out = (float*)d_out;

    // workspace layout (floats): dinv[100096] | h1[NN*64] | agg1[NN*64] | h2[NN*16]
    float* dinv = (float*)d_ws;
    float* h1   = dinv + 100096;               // aligned past N
    float* agg1 = h1 + (size_t)NN * HF;
    float* h2   = agg1 + (size_t)NN * HF;

    hipMemsetAsync(agg1, 0, (size_t)NN * HF * sizeof(float), stream);
    hipMemsetAsync(out, 0, (size_t)out_size * sizeof(float), stream);

    k_init_deg<<<(NN + 255) / 256, 256, 0, stream>>>(dinv);
    k_accum_deg<<<(NE + 255) / 256, 256, 0, stream>>>(dst, dinv);
    k_dinv<<<(NN + 255) / 256, 256, 0, stream>>>(dinv);

    k_gemm1<<<(NN + 15) / 16, 256, 0, stream>>>(x, W1, h1);
    k_aggregate1<<<(NE * 64) / 256, 256, 0, stream>>>(src, dst, dinv, h1, agg1);
    k_finalize1<<<(NN * HF + 255) / 256, 256, 0, stream>>>(h1, dinv, b1, agg1);

    k_gemm2<<<(NN + 15) / 16, 256, 0, stream>>>(agg1, W2, h2);
    k_aggregate2<<<(NE * 16) / 256, 256, 0, stream>>>(src, dst, dinv, h2, out);
    k_finalize2<<<(NN * OF + 255) / 256, 256, 0, stream>>>(h2, dinv, b2, out);
}

// Round 2
// 348.509 us; speedup vs baseline: 1.7534x; 1.7534x over previous
//
#include <hip/hip_runtime.h>

namespace {
constexpr int NN  = 100000;   // nodes
constexpr int NE  = 1000000;  // edges
constexpr int INF = 256;
constexpr int HF  = 64;
constexpr int OF  = 16;
constexpr int SCAN_CHUNK = 1024;                       // elems per scan block (256 thr x 4)
constexpr int NBLK = (NN + SCAN_CHUNK - 1) / SCAN_CHUNK; // 98
}

// ---- degree histogram (int) ------------------------------------------------

__global__ void k_hist(const int* __restrict__ dst, int* __restrict__ cnt) {
    int e = blockIdx.x * 256 + threadIdx.x;
    if (e < NE) atomicAdd(&cnt[dst[e]], 1);
}

__global__ void k_dinv(const int* __restrict__ cnt, float* __restrict__ dinv) {
    int v = blockIdx.x * 256 + threadIdx.x;
    if (v < NN) dinv[v] = rsqrtf((float)(cnt[v] + 1));   // +1 self-loop
}

// ---- 2-level exclusive scan of cnt -> rowptr -------------------------------

__global__ __launch_bounds__(256) void k_reduce(const int* __restrict__ cnt,
                                                int* __restrict__ bsum) {
    int t = threadIdx.x;
    int i0 = blockIdx.x * SCAN_CHUNK + t * 4;
    int s = 0;
    #pragma unroll
    for (int q = 0; q < 4; ++q) if (i0 + q < NN) s += cnt[i0 + q];
    #pragma unroll
    for (int off = 32; off > 0; off >>= 1) s += __shfl_down(s, off);
    __shared__ int wsum[4];
    int lane = t & 63, wid = t >> 6;
    if (lane == 0) wsum[wid] = s;
    __syncthreads();
    if (t == 0) bsum[blockIdx.x] = wsum[0] + wsum[1] + wsum[2] + wsum[3];
}

__global__ void k_scan_partials(int* __restrict__ bsum) {
    if (threadIdx.x == 0) {
        int run = 0;
        for (int i = 0; i < NBLK; ++i) { int t = bsum[i]; bsum[i] = run; run += t; }
    }
}

__global__ __launch_bounds__(256) void k_scan(const int* __restrict__ cnt,
                                              const int* __restrict__ bsum,
                                              int* __restrict__ rowptr,
                                              int* __restrict__ cursor) {
    int t = threadIdx.x;
    int i0 = blockIdx.x * SCAN_CHUNK + t * 4;
    int v0 = 0, v1 = 0, v2 = 0, v3 = 0;
    if (i0 + 0 < NN) v0 = cnt[i0 + 0];
    if (i0 + 1 < NN) v1 = cnt[i0 + 1];
    if (i0 + 2 < NN) v2 = cnt[i0 + 2];
    if (i0 + 3 < NN) v3 = cnt[i0 + 3];
    int tsum = v0 + v1 + v2 + v3;
    int lane = t & 63, wid = t >> 6;
    int incl = tsum;
    #pragma unroll
    for (int off = 1; off < 64; off <<= 1) {
        int n = __shfl_up(incl, off);
        if (lane >= off) incl += n;
    }
    __shared__ int wsum[4];
    if (lane == 63) wsum[wid] = incl;
    __syncthreads();
    int woff = 0;
    for (int w = 0; w < wid; ++w) woff += wsum[w];
    int excl = woff + (incl - tsum) + bsum[blockIdx.x];
    int e0 = excl, e1 = e0 + v0, e2 = e1 + v1, e3 = e2 + v2;
    if (i0 + 0 < NN) { rowptr[i0 + 0] = e0; cursor[i0 + 0] = e0; }
    if (i0 + 1 < NN) { rowptr[i0 + 1] = e1; cursor[i0 + 1] = e1; }
    if (i0 + 2 < NN) { rowptr[i0 + 2] = e2; cursor[i0 + 2] = e2; }
    if (i0 + 3 < NN) { rowptr[i0 + 3] = e3; cursor[i0 + 3] = e3; }
    if (i0 + 3 == NN - 1) rowptr[NN] = e3 + v3;
}

__global__ void k_scatter(const int* __restrict__ src, const int* __restrict__ dst,
                          int* __restrict__ cursor, int* __restrict__ eidx) {
    int e = blockIdx.x * 256 + threadIdx.x;
    if (e < NE) {
        int p = atomicAdd(&cursor[dst[e]], 1);
        eidx[p] = src[e];
    }
}

// ---- GEMM1: h1 = x @ W1  [NN,256]x[256,64], LDS-tiled 64x64 ----------------
// 256 threads: thread (tr=t>>4, tc=t&15) computes rows 4tr..+3, cols 4tc..+3.
// K staged in halves of 128. xs stride 132, ws stride 68 (bank-friendly, 16B-aligned).
__global__ __launch_bounds__(256, 2) void k_gemm1(const float* __restrict__ x,
                                                  const float* __restrict__ W1,
                                                  float* __restrict__ h1) {
    __shared__ float xs[64 * 132];
    __shared__ float ws[128 * 68];
    int t = threadIdx.x;
    int row0 = blockIdx.x * 64;
    int tr4 = (t >> 4) * 4;
    int tc4 = (t & 15) * 4;
    float acc[4][4] = {};
    for (int kb = 0; kb < INF; kb += 128) {
        __syncthreads();   // LDS reuse guard
        // stage x tile: 64 rows x 128 cols (clamped rows for the tail block)
        {
            int col = (t & 31) * 4;
            int rw  = t >> 5;
            #pragma unroll
            for (int p = 0; p < 8; ++p) {
                int r = rw + p * 8;
                int gr = row0 + r; if (gr > NN - 1) gr = NN - 1;
                float4 v = *(const float4*)(x + (size_t)gr * INF + kb + col);
                *(float4*)(xs + r * 132 + col) = v;
            }
        }
        // stage W tile: 128 k-rows x 64 cols
        {
            #pragma unroll
            for (int p = 0; p < 8; ++p) {
                int idx = p * 1024 + t * 4;
                int r = idx >> 6;
                int cc = idx & 63;
                float4 v = *(const float4*)(W1 + (size_t)(kb + r) * HF + cc);
                *(float4*)(ws + r * 68 + cc) = v;
            }
        }
        __syncthreads();
        #pragma unroll 4
        for (int k = 0; k < 128; k += 4) {
            float4 xv[4];
            #pragma unroll
            for (int i = 0; i < 4; ++i)
                xv[i] = *(const float4*)(xs + (tr4 + i) * 132 + k);
            #pragma unroll
            for (int q = 0; q < 4; ++q) {
                float4 wv = *(const float4*)(ws + (k + q) * 68 + tc4);
                #pragma unroll
                for (int i = 0; i < 4; ++i) {
                    float xq = ((const float*)&xv[i])[q];
                    acc[i][0] += xq * wv.x;
                    acc[i][1] += xq * wv.y;
                    acc[i][2] += xq * wv.z;
                    acc[i][3] += xq * wv.w;
                }
            }
        }
    }
    #pragma unroll
    for (int i = 0; i < 4; ++i) {
        int gr = row0 + tr4 + i;
        if (gr < NN) {
            float4 o = {acc[i][0], acc[i][1], acc[i][2], acc[i][3]};
            *(float4*)(h1 + (size_t)gr * HF + tc4) = o;
        }
    }
}

// ---- Gather-aggregate layer 1 (fused self-loop + bias + relu) --------------
// one wave per node; lane = feature
__global__ __launch_bounds__(256) void k_gather1(const int* __restrict__ rowptr,
                                                 const int* __restrict__ eidx,
                                                 const float* __restrict__ dinv,
                                                 const float* __restrict__ h1,
                                                 const float* __restrict__ b1,
                                                 float* __restrict__ hr) {
    int gid = blockIdx.x * 256 + threadIdx.x;
    int v = gid >> 6, j = gid & 63;
    int beg = rowptr[v], end = rowptr[v + 1];
    float acc = 0.f;
    for (int i = beg; i < end; ++i) {
        int s = eidx[i];
        acc += dinv[s] * h1[(size_t)s * HF + j];
    }
    float dv = dinv[v];
    float val = dv * acc + dv * dv * h1[(size_t)v * HF + j] + b1[j];
    hr[(size_t)v * HF + j] = val > 0.f ? val : 0.f;
}

// ---- GEMM2: h2 = hr @ W2  [NN,64]x[64,16] ----------------------------------
__global__ __launch_bounds__(256) void k_gemm2(const float* __restrict__ h,
                                               const float* __restrict__ W2,
                                               float* __restrict__ h2) {
    int j   = threadIdx.x & 15;
    int r   = threadIdx.x >> 4;
    int row = blockIdx.x * 16 + r;
    if (row >= NN) return;
    const float* hrow = h + (size_t)row * HF;
    float acc = 0.f;
    #pragma unroll
    for (int k = 0; k < HF; k += 4) {
        float4 hv = *(const float4*)(hrow + k);
        acc += hv.x * W2[(k + 0) * OF + j];
        acc += hv.y * W2[(k + 1) * OF + j];
        acc += hv.z * W2[(k + 2) * OF + j];
        acc += hv.w * W2[(k + 3) * OF + j];
    }
    h2[(size_t)row * OF + j] = acc;
}

// ---- Gather-aggregate layer 2 (fused self-loop + bias) ---------------------
// 16 lanes per node, 16 nodes per block
__global__ __launch_bounds__(256) void k_gather2(const int* __restrict__ rowptr,
                                                 const int* __restrict__ eidx,
                                                 const float* __restrict__ dinv,
                                                 const float* __restrict__ h2,
                                                 const float* __restrict__ b2,
                                                 float* __restrict__ out) {
    int gid = blockIdx.x * 256 + threadIdx.x;
    int v = gid >> 4, j = gid & 15;
    int beg = rowptr[v], end = rowptr[v + 1];
    float acc = 0.f;
    for (int i = beg; i < end; ++i) {
        int s = eidx[i];
        acc += dinv[s] * h2[(size_t)s * OF + j];
    }
    float dv = dinv[v];
    out[(size_t)v * OF + j] = dv * acc + dv * dv * h2[(size_t)v * OF + j] + b2[j];
}

extern "C" void kernel_launch(void* const* d_in, const int* in_sizes, int n_in,
                              void* d_out, int out_size, void* d_ws, size_t ws_size,
                              hipStream_t stream) {
    const float* x   = (const float*)d_in[0];
    const int*   ei  = (const int*)d_in[1];
    const int*   src = ei;            // edge_index[0]
    const int*   dst = ei + NE;       // edge_index[1]
    const float* W1  = (const float*)d_in[2];
    const float* b1  = (const float*)d_in[3];
    const float* W2  = (const float*)d_in[4];
    const float* b2  = (const float*)d_in[5];
    float* out = (float*)d_out;

    // workspace layout (4B units)
    float* dinv   = (float*)d_ws;                       // [100096]
    float* h1     = dinv + 100096;                      // [NN*64]
    float* hr     = h1 + (size_t)NN * HF;               // [NN*64]
    float* h2     = hr + (size_t)NN * HF;               // [NN*16]
    int*   cnt    = (int*)(h2 + (size_t)NN * OF);       // [100096]
    int*   rowptr = cnt + 100096;                       // [100352] (incl. rowptr[NN])
    int*   cursor = rowptr + 100352;                    // [100096]
    int*   eidx   = cursor + 100096;                    // [NE]
    int*   bsum   = eidx + NE;                          // [128]

    hipMemsetAsync(cnt, 0, 100096 * sizeof(int), stream);

    // CSR build + norms
    k_hist<<<(NE + 255) / 256, 256, 0, stream>>>(dst, cnt);
    k_dinv<<<(NN + 255) / 256, 256, 0, stream>>>(cnt, dinv);
    k_reduce<<<NBLK, 256, 0, stream>>>(cnt, bsum);
    k_scan_partials<<<1, 64, 0, stream>>>(bsum);
    k_scan<<<NBLK, 256, 0, stream>>>(cnt, bsum, rowptr, cursor);
    k_scatter<<<(NE + 255) / 256, 256, 0, stream>>>(src, dst, cursor, eidx);

    // layer 1
    k_gemm1<<<(NN + 63) / 64, 256, 0, stream>>>(x, W1, h1);
    k_gather1<<<(NN * HF) / 256, 256, 0, stream>>>(rowptr, eidx, dinv, h1, b1, hr);

    // layer 2
    k_gemm2<<<(NN + 15) / 16, 256, 0, stream>>>(hr, W2, h2);
    k_gather2<<<(NN * OF) / 256, 256, 0, stream>>>(rowptr, eidx, dinv, h2, b2, out);
}

// Round 3
// 286.994 us; speedup vs baseline: 2.1292x; 1.2143x over previous
//
#include <hip/hip_runtime.h>

namespace {
constexpr int NN  = 100000;   // nodes
constexpr int NE  = 1000000;  // edges
constexpr int INF = 256;
constexpr int HF  = 64;
constexpr int OF  = 16;
constexpr int SCAN_CHUNK = 1024;                       // elems per scan block (256 thr x 4)
constexpr int NBLK = (NN + SCAN_CHUNK - 1) / SCAN_CHUNK; // 98
}

// ---- degree histogram (int) ------------------------------------------------

__global__ void k_hist(const int* __restrict__ dst, int* __restrict__ cnt) {
    int e = blockIdx.x * 256 + threadIdx.x;
    if (e < NE) atomicAdd(&cnt[dst[e]], 1);
}

__global__ void k_dinv(const int* __restrict__ cnt, float* __restrict__ dinv) {
    int v = blockIdx.x * 256 + threadIdx.x;
    if (v < NN) dinv[v] = rsqrtf((float)(cnt[v] + 1));   // +1 self-loop
}

// ---- 2-level exclusive scan of cnt -> rowptr -------------------------------

__global__ __launch_bounds__(256) void k_reduce(const int* __restrict__ cnt,
                                                int* __restrict__ bsum) {
    int t = threadIdx.x;
    int i0 = blockIdx.x * SCAN_CHUNK + t * 4;
    int s = 0;
    #pragma unroll
    for (int q = 0; q < 4; ++q) if (i0 + q < NN) s += cnt[i0 + q];
    #pragma unroll
    for (int off = 32; off > 0; off >>= 1) s += __shfl_down(s, off);
    __shared__ int wsum[4];
    int lane = t & 63, wid = t >> 6;
    if (lane == 0) wsum[wid] = s;
    __syncthreads();
    if (t == 0) bsum[blockIdx.x] = wsum[0] + wsum[1] + wsum[2] + wsum[3];
}

__global__ void k_scan_partials(int* __restrict__ bsum) {
    if (threadIdx.x == 0) {
        int run = 0;
        for (int i = 0; i < NBLK; ++i) { int t = bsum[i]; bsum[i] = run; run += t; }
    }
}

__global__ __launch_bounds__(256) void k_scan(const int* __restrict__ cnt,
                                              const int* __restrict__ bsum,
                                              int* __restrict__ rowptr,
                                              int* __restrict__ cursor) {
    int t = threadIdx.x;
    int i0 = blockIdx.x * SCAN_CHUNK + t * 4;
    int v0 = 0, v1 = 0, v2 = 0, v3 = 0;
    if (i0 + 0 < NN) v0 = cnt[i0 + 0];
    if (i0 + 1 < NN) v1 = cnt[i0 + 1];
    if (i0 + 2 < NN) v2 = cnt[i0 + 2];
    if (i0 + 3 < NN) v3 = cnt[i0 + 3];
    int tsum = v0 + v1 + v2 + v3;
    int lane = t & 63, wid = t >> 6;
    int incl = tsum;
    #pragma unroll
    for (int off = 1; off < 64; off <<= 1) {
        int n = __shfl_up(incl, off);
        if (lane >= off) incl += n;
    }
    __shared__ int wsum[4];
    if (lane == 63) wsum[wid] = incl;
    __syncthreads();
    int woff = 0;
    for (int w = 0; w < wid; ++w) woff += wsum[w];
    int excl = woff + (incl - tsum) + bsum[blockIdx.x];
    int e0 = excl, e1 = e0 + v0, e2 = e1 + v1, e3 = e2 + v2;
    if (i0 + 0 < NN) { rowptr[i0 + 0] = e0; cursor[i0 + 0] = e0; }
    if (i0 + 1 < NN) { rowptr[i0 + 1] = e1; cursor[i0 + 1] = e1; }
    if (i0 + 2 < NN) { rowptr[i0 + 2] = e2; cursor[i0 + 2] = e2; }
    if (i0 + 3 < NN) { rowptr[i0 + 3] = e3; cursor[i0 + 3] = e3; }
    if (i0 + 3 == NN - 1) rowptr[NN] = e3 + v3;
}

__global__ void k_scatter(const int* __restrict__ src, const int* __restrict__ dst,
                          int* __restrict__ cursor, int* __restrict__ eidx) {
    int e = blockIdx.x * 256 + threadIdx.x;
    if (e < NE) {
        int p = atomicAdd(&cursor[dst[e]], 1);
        eidx[p] = src[e];
    }
}

// ---- GEMM1: h1 = x @ W1  [NN,256]x[256,64], LDS-tiled 64x64 ----------------
__global__ __launch_bounds__(256, 2) void k_gemm1(const float* __restrict__ x,
                                                  const float* __restrict__ W1,
                                                  float* __restrict__ h1) {
    __shared__ float xs[64 * 132];
    __shared__ float ws[128 * 68];
    int t = threadIdx.x;
    int row0 = blockIdx.x * 64;
    int tr4 = (t >> 4) * 4;
    int tc4 = (t & 15) * 4;
    float acc[4][4] = {};
    for (int kb = 0; kb < INF; kb += 128) {
        __syncthreads();   // LDS reuse guard
        {
            int col = (t & 31) * 4;
            int rw  = t >> 5;
            #pragma unroll
            for (int p = 0; p < 8; ++p) {
                int r = rw + p * 8;
                int gr = row0 + r; if (gr > NN - 1) gr = NN - 1;
                float4 v = *(const float4*)(x + (size_t)gr * INF + kb + col);
                *(float4*)(xs + r * 132 + col) = v;
            }
        }
        {
            #pragma unroll
            for (int p = 0; p < 8; ++p) {
                int idx = p * 1024 + t * 4;
                int r = idx >> 6;
                int cc = idx & 63;
                float4 v = *(const float4*)(W1 + (size_t)(kb + r) * HF + cc);
                *(float4*)(ws + r * 68 + cc) = v;
            }
        }
        __syncthreads();
        #pragma unroll 4
        for (int k = 0; k < 128; k += 4) {
            float4 xv[4];
            #pragma unroll
            for (int i = 0; i < 4; ++i)
                xv[i] = *(const float4*)(xs + (tr4 + i) * 132 + k);
            #pragma unroll
            for (int q = 0; q < 4; ++q) {
                float4 wv = *(const float4*)(ws + (k + q) * 68 + tc4);
                #pragma unroll
                for (int i = 0; i < 4; ++i) {
                    float xq = ((const float*)&xv[i])[q];
                    acc[i][0] += xq * wv.x;
                    acc[i][1] += xq * wv.y;
                    acc[i][2] += xq * wv.z;
                    acc[i][3] += xq * wv.w;
                }
            }
        }
    }
    #pragma unroll
    for (int i = 0; i < 4; ++i) {
        int gr = row0 + tr4 + i;
        if (gr < NN) {
            float4 o = {acc[i][0], acc[i][1], acc[i][2], acc[i][3]};
            *(float4*)(h1 + (size_t)gr * HF + tc4) = o;
        }
    }
}

// ---- Gather-aggregate layer 1 (fused self-loop + bias + relu) --------------
// one wave per node; 4 edge slots x 16 feature groups (float4 each)
__global__ __launch_bounds__(256) void k_gather1(const int* __restrict__ rowptr,
                                                 const int* __restrict__ eidx,
                                                 const float* __restrict__ dinv,
                                                 const float* __restrict__ h1,
                                                 const float* __restrict__ b1,
                                                 float* __restrict__ hr) {
    int gid   = blockIdx.x * 256 + threadIdx.x;
    int v     = gid >> 6;
    int lane  = threadIdx.x & 63;
    int eslot = lane >> 4;        // 0..3
    int fg    = lane & 15;        // float4 group -> feats 4fg..4fg+3
    int beg = rowptr[v], end = rowptr[v + 1];
    float4 acc = {0.f, 0.f, 0.f, 0.f};
    for (int i = beg + eslot; i < end; i += 4) {
        int s = eidx[i];
        float w = dinv[s];
        float4 hv = *(const float4*)(h1 + (size_t)s * HF + fg * 4);
        acc.x += w * hv.x; acc.y += w * hv.y; acc.z += w * hv.z; acc.w += w * hv.w;
    }
    #pragma unroll
    for (int m = 16; m <= 32; m <<= 1) {
        acc.x += __shfl_xor(acc.x, m);
        acc.y += __shfl_xor(acc.y, m);
        acc.z += __shfl_xor(acc.z, m);
        acc.w += __shfl_xor(acc.w, m);
    }
    if (eslot == 0) {
        float dv = dinv[v];
        float sl = dv * dv;
        float4 hv = *(const float4*)(h1 + (size_t)v * HF + fg * 4);
        float4 bv = *(const float4*)(b1 + fg * 4);
        float4 o;
        o.x = dv * acc.x + sl * hv.x + bv.x;
        o.y = dv * acc.y + sl * hv.y + bv.y;
        o.z = dv * acc.z + sl * hv.z + bv.z;
        o.w = dv * acc.w + sl * hv.w + bv.w;
        o.x = o.x > 0.f ? o.x : 0.f;
        o.y = o.y > 0.f ? o.y : 0.f;
        o.z = o.z > 0.f ? o.z : 0.f;
        o.w = o.w > 0.f ? o.w : 0.f;
        *(float4*)(hr + (size_t)v * HF + fg * 4) = o;
    }
}

// ---- GEMM2: h2 = hr @ W2  [NN,64]x[64,16] ----------------------------------
__global__ __launch_bounds__(256) void k_gemm2(const float* __restrict__ h,
                                               const float* __restrict__ W2,
                                               float* __restrict__ h2) {
    int j   = threadIdx.x & 15;
    int r   = threadIdx.x >> 4;
    int row = blockIdx.x * 16 + r;
    if (row >= NN) return;
    const float* hrow = h + (size_t)row * HF;
    float acc = 0.f;
    #pragma unroll
    for (int k = 0; k < HF; k += 4) {
        float4 hv = *(const float4*)(hrow + k);
        acc += hv.x * W2[(k + 0) * OF + j];
        acc += hv.y * W2[(k + 1) * OF + j];
        acc += hv.z * W2[(k + 2) * OF + j];
        acc += hv.w * W2[(k + 3) * OF + j];
    }
    h2[(size_t)row * OF + j] = acc;
}

// ---- Gather-aggregate layer 2 (fused self-loop + bias) ---------------------
// one wave per node; 16 edge slots x 4 lanes (float4 = 16 feats)
__global__ __launch_bounds__(256) void k_gather2(const int* __restrict__ rowptr,
                                                 const int* __restrict__ eidx,
                                                 const float* __restrict__ dinv,
                                                 const float* __restrict__ h2,
                                                 const float* __restrict__ b2,
                                                 float* __restrict__ out) {
    int gid   = blockIdx.x * 256 + threadIdx.x;
    int v     = gid >> 6;
    int lane  = threadIdx.x & 63;
    int eslot = lane >> 2;        // 0..15
    int fg    = lane & 3;         // float4 group -> feats 4fg..4fg+3
    int beg = rowptr[v], end = rowptr[v + 1];
    float4 acc = {0.f, 0.f, 0.f, 0.f};
    for (int i = beg + eslot; i < end; i += 16) {
        int s = eidx[i];
        float w = dinv[s];
        float4 hv = *(const float4*)(h2 + (size_t)s * OF + fg * 4);
        acc.x += w * hv.x; acc.y += w * hv.y; acc.z += w * hv.z; acc.w += w * hv.w;
    }
    #pragma unroll
    for (int m = 4; m <= 32; m <<= 1) {
        acc.x += __shfl_xor(acc.x, m);
        acc.y += __shfl_xor(acc.y, m);
        acc.z += __shfl_xor(acc.z, m);
        acc.w += __shfl_xor(acc.w, m);
    }
    if (eslot == 0) {
        float dv = dinv[v];
        float sl = dv * dv;
        float4 hv = *(const float4*)(h2 + (size_t)v * OF + fg * 4);
        float4 bv = *(const float4*)(b2 + fg * 4);
        float4 o;
        o.x = dv * acc.x + sl * hv.x + bv.x;
        o.y = dv * acc.y + sl * hv.y + bv.y;
        o.z = dv * acc.z + sl * hv.z + bv.z;
        o.w = dv * acc.w + sl * hv.w + bv.w;
        *(float4*)(out + (size_t)v * OF + fg * 4) = o;
    }
}

extern "C" void kernel_launch(void* const* d_in, const int* in_sizes, int n_in,
                              void* d_out, int out_size, void* d_ws, size_t ws_size,
                              hipStream_t stream) {
    const float* x   = (const float*)d_in[0];
    const int*   ei  = (const int*)d_in[1];
    const int*   src = ei;            // edge_index[0]
    const int*   dst = ei + NE;       // edge_index[1]
    const float* W1  = (const float*)d_in[2];
    const float* b1  = (const float*)d_in[3];
    const float* W2  = (const float*)d_in[4];
    const float* b2  = (const float*)d_in[5];
    float* out = (float*)d_out;

    // workspace layout (4B units)
    float* dinv   = (float*)d_ws;                       // [100096]
    float* h1     = dinv + 100096;                      // [NN*64]
    float* hr     = h1 + (size_t)NN * HF;               // [NN*64]
    float* h2     = hr + (size_t)NN * HF;               // [NN*16]
    int*   cnt    = (int*)(h2 + (size_t)NN * OF);       // [100096]
    int*   rowptr = cnt + 100096;                       // [100352] (incl. rowptr[NN])
    int*   cursor = rowptr + 100352;                    // [100096]
    int*   eidx   = cursor + 100096;                    // [NE]
    int*   bsum   = eidx + NE;                          // [128]

    hipMemsetAsync(cnt, 0, 100096 * sizeof(int), stream);

    // CSR build + norms
    k_hist<<<(NE + 255) / 256, 256, 0, stream>>>(dst, cnt);
    k_dinv<<<(NN + 255) / 256, 256, 0, stream>>>(cnt, dinv);
    k_reduce<<<NBLK, 256, 0, stream>>>(cnt, bsum);
    k_scan_partials<<<1, 64, 0, stream>>>(bsum);
    k_scan<<<NBLK, 256, 0, stream>>>(cnt, bsum, rowptr, cursor);
    k_scatter<<<(NE + 255) / 256, 256, 0, stream>>>(src, dst, cursor, eidx);

    // layer 1
    k_gemm1<<<(NN + 63) / 64, 256, 0, stream>>>(x, W1, h1);
    k_gather1<<<(NN * HF) / 256, 256, 0, stream>>>(rowptr, eidx, dinv, h1, b1, hr);

    // layer 2
    k_gemm2<<<(NN + 15) / 16, 256, 0, stream>>>(hr, W2, h2);
    k_gather2<<<(NN * HF) / 256, 256, 0, stream>>>(rowptr, eidx, dinv, h2, b2, out);
}

// Round 4
// 273.480 us; speedup vs baseline: 2.2344x; 1.0494x over previous
//
#include <hip/hip_runtime.h>

namespace {
constexpr int NN  = 100000;   // nodes
constexpr int NE  = 1000000;  // edges
constexpr int INF = 256;
constexpr int HF  = 64;
constexpr int OF  = 16;
constexpr int SCAN_CHUNK = 1024;                       // elems per scan block (256 thr x 4)
constexpr int NBLK = (NN + SCAN_CHUNK - 1) / SCAN_CHUNK; // 98
}

typedef __attribute__((ext_vector_type(8))) short     sh8;
typedef __attribute__((ext_vector_type(4))) float     f32x4;
typedef __attribute__((ext_vector_type(4))) unsigned short us4;
typedef __attribute__((ext_vector_type(8))) unsigned short us8;

__device__ __forceinline__ unsigned short f2bf(float f) {
    unsigned int u = __builtin_bit_cast(unsigned int, f);
    u += 0x7FFFu + ((u >> 16) & 1u);       // round-to-nearest-even
    return (unsigned short)(u >> 16);
}

// ---- degree histogram (int) ------------------------------------------------

__global__ void k_hist(const int* __restrict__ dst, int* __restrict__ cnt) {
    int e = blockIdx.x * 256 + threadIdx.x;
    if (e < NE) atomicAdd(&cnt[dst[e]], 1);
}

__global__ void k_dinv(const int* __restrict__ cnt, float* __restrict__ dinv) {
    int v = blockIdx.x * 256 + threadIdx.x;
    if (v < NN) dinv[v] = rsqrtf((float)(cnt[v] + 1));   // +1 self-loop
}

// ---- 2-level exclusive scan of cnt -> rowptr -------------------------------

__global__ __launch_bounds__(256) void k_reduce(const int* __restrict__ cnt,
                                                int* __restrict__ bsum) {
    int t = threadIdx.x;
    int i0 = blockIdx.x * SCAN_CHUNK + t * 4;
    int s = 0;
    #pragma unroll
    for (int q = 0; q < 4; ++q) if (i0 + q < NN) s += cnt[i0 + q];
    #pragma unroll
    for (int off = 32; off > 0; off >>= 1) s += __shfl_down(s, off);
    __shared__ int wsum[4];
    int lane = t & 63, wid = t >> 6;
    if (lane == 0) wsum[wid] = s;
    __syncthreads();
    if (t == 0) bsum[blockIdx.x] = wsum[0] + wsum[1] + wsum[2] + wsum[3];
}

__global__ void k_scan_partials(int* __restrict__ bsum) {
    if (threadIdx.x == 0) {
        int run = 0;
        for (int i = 0; i < NBLK; ++i) { int t = bsum[i]; bsum[i] = run; run += t; }
    }
}

__global__ __launch_bounds__(256) void k_scan(const int* __restrict__ cnt,
                                              const int* __restrict__ bsum,
                                              int* __restrict__ rowptr,
                                              int* __restrict__ cursor) {
    int t = threadIdx.x;
    int i0 = blockIdx.x * SCAN_CHUNK + t * 4;
    int v0 = 0, v1 = 0, v2 = 0, v3 = 0;
    if (i0 + 0 < NN) v0 = cnt[i0 + 0];
    if (i0 + 1 < NN) v1 = cnt[i0 + 1];
    if (i0 + 2 < NN) v2 = cnt[i0 + 2];
    if (i0 + 3 < NN) v3 = cnt[i0 + 3];
    int tsum = v0 + v1 + v2 + v3;
    int lane = t & 63, wid = t >> 6;
    int incl = tsum;
    #pragma unroll
    for (int off = 1; off < 64; off <<= 1) {
        int n = __shfl_up(incl, off);
        if (lane >= off) incl += n;
    }
    __shared__ int wsum[4];
    if (lane == 63) wsum[wid] = incl;
    __syncthreads();
    int woff = 0;
    for (int w = 0; w < wid; ++w) woff += wsum[w];
    int excl = woff + (incl - tsum) + bsum[blockIdx.x];
    int e0 = excl, e1 = e0 + v0, e2 = e1 + v1, e3 = e2 + v2;
    if (i0 + 0 < NN) { rowptr[i0 + 0] = e0; cursor[i0 + 0] = e0; }
    if (i0 + 1 < NN) { rowptr[i0 + 1] = e1; cursor[i0 + 1] = e1; }
    if (i0 + 2 < NN) { rowptr[i0 + 2] = e2; cursor[i0 + 2] = e2; }
    if (i0 + 3 < NN) { rowptr[i0 + 3] = e3; cursor[i0 + 3] = e3; }
    if (i0 + 3 == NN - 1) rowptr[NN] = e3 + v3;
}

__global__ void k_scatter(const int* __restrict__ src, const int* __restrict__ dst,
                          int* __restrict__ cursor, int* __restrict__ eidx) {
    int e = blockIdx.x * 256 + threadIdx.x;
    if (e < NE) {
        int p = atomicAdd(&cursor[dst[e]], 1);
        eidx[p] = src[e];
    }
}

// ---- GEMM1: h1 = x @ W1  [NN,256]x[256,64], bf16 MFMA ----------------------
// 128 rows/block, 4 waves; wave w owns rows w*32..w*32+31 (two 16-row M-tiles)
// x full K staged in halves of 128 (fp32 -> bf16 into LDS).
// W1 staged once per block, transposed: wt[col][k] (bf16), so B-frag = 16B
// contiguous along K.  MFMA 16x16x32 bf16: A/B lane&15 = m/n, (lane>>4)*8+j = k;
// D row=(lane>>4)*4+r, col=lane&15 (guide-verified m89/m91).
__global__ __launch_bounds__(256, 2) void k_gemm1(const float* __restrict__ x,
                                                  const float* __restrict__ W1,
                                                  float* __restrict__ h1) {
    __shared__ unsigned short xs[128 * 136];   // stride 136 (272B = 17*16, 2-way banks)
    __shared__ unsigned short wt[64 * 264];    // stride 264 (528B = 33*16, 2-way banks)
    int t = threadIdx.x;
    int w = t >> 6, l = t & 63;
    int row0 = blockIdx.x * 128;

    // stage W1 transposed -> wt[c][k], once per block (W1 is 64KB, L2-hot)
    #pragma unroll
    for (int p = 0; p < 8; ++p) {
        int T   = p * 256 + t;       // 2048 tasks: 64 cols x 32 k-blocks
        int c   = T >> 5;
        int kb8 = T & 31;            // k-block of 8
        const float* wp = W1 + (size_t)(kb8 * 8) * HF + c;
        us8 b;
        #pragma unroll
        for (int j = 0; j < 8; ++j) b[j] = f2bf(wp[j * HF]);
        *(us8*)(wt + c * 264 + kb8 * 8) = b;
    }

    f32x4 acc[2][4];
    #pragma unroll
    for (int i = 0; i < 2; ++i)
        #pragma unroll
        for (int j = 0; j < 4; ++j) acc[i][j] = (f32x4){0.f, 0.f, 0.f, 0.f};

    for (int kb = 0; kb < INF; kb += 128) {
        // stage x tile: 128 rows x 128 cols, fp32 -> bf16
        #pragma unroll
        for (int p = 0; p < 16; ++p) {
            int q    = p * 256 + t;      // 4096 float4 tasks
            int r    = q >> 5;           // row 0..127
            int col4 = q & 31;           // float4 index within the 128-col half
            int gr   = row0 + r; if (gr > NN - 1) gr = NN - 1;
            float4 v = *(const float4*)(x + (size_t)gr * INF + kb + col4 * 4);
            us4 b = { f2bf(v.x), f2bf(v.y), f2bf(v.z), f2bf(v.w) };
            *(us4*)(xs + r * 136 + col4 * 4) = b;
        }
        __syncthreads();   // xs ready (and wt on first iter)
        #pragma unroll
        for (int ks = 0; ks < 4; ++ks) {
            int k0 = ks * 32 + (l >> 4) * 8;      // lane's k within the 128-half
            sh8 a0 = *(const sh8*)(xs + (w * 32 +      (l & 15)) * 136 + k0);
            sh8 a1 = *(const sh8*)(xs + (w * 32 + 16 + (l & 15)) * 136 + k0);
            #pragma unroll
            for (int nt = 0; nt < 4; ++nt) {
                sh8 b = *(const sh8*)(wt + (nt * 16 + (l & 15)) * 264 + kb + k0);
                acc[0][nt] = __builtin_amdgcn_mfma_f32_16x16x32_bf16(a0, b, acc[0][nt], 0, 0, 0);
                acc[1][nt] = __builtin_amdgcn_mfma_f32_16x16x32_bf16(a1, b, acc[1][nt], 0, 0, 0);
            }
        }
        __syncthreads();   // protect xs before next half's staging
    }

    // epilogue: D row=(l>>4)*4+r, col=l&15
    #pragma unroll
    for (int mt = 0; mt < 2; ++mt) {
        #pragma unroll
        for (int r = 0; r < 4; ++r) {
            int gr = row0 + w * 32 + mt * 16 + (l >> 4) * 4 + r;
            if (gr < NN) {
                #pragma unroll
                for (int nt = 0; nt < 4; ++nt)
                    h1[(size_t)gr * HF + nt * 16 + (l & 15)] = acc[mt][nt][r];
            }
        }
    }
}

// ---- Gather-aggregate layer 1 (fused self-loop + bias + relu) --------------
// one wave per node; 4 edge slots x 16 feature groups (float4 each)
__global__ __launch_bounds__(256) void k_gather1(const int* __restrict__ rowptr,
                                                 const int* __restrict__ eidx,
                                                 const float* __restrict__ dinv,
                                                 const float* __restrict__ h1,
                                                 const float* __restrict__ b1,
                                                 float* __restrict__ hr) {
    int gid   = blockIdx.x * 256 + threadIdx.x;
    int v     = gid >> 6;
    int lane  = threadIdx.x & 63;
    int eslot = lane >> 4;        // 0..3
    int fg    = lane & 15;        // float4 group -> feats 4fg..4fg+3
    int beg = rowptr[v], end = rowptr[v + 1];
    float4 acc = {0.f, 0.f, 0.f, 0.f};
    for (int i = beg + eslot; i < end; i += 4) {
        int s = eidx[i];
        float w = dinv[s];
        float4 hv = *(const float4*)(h1 + (size_t)s * HF + fg * 4);
        acc.x += w * hv.x; acc.y += w * hv.y; acc.z += w * hv.z; acc.w += w * hv.w;
    }
    #pragma unroll
    for (int m = 16; m <= 32; m <<= 1) {
        acc.x += __shfl_xor(acc.x, m);
        acc.y += __shfl_xor(acc.y, m);
        acc.z += __shfl_xor(acc.z, m);
        acc.w += __shfl_xor(acc.w, m);
    }
    if (eslot == 0) {
        float dv = dinv[v];
        float sl = dv * dv;
        float4 hv = *(const float4*)(h1 + (size_t)v * HF + fg * 4);
        float4 bv = *(const float4*)(b1 + fg * 4);
        float4 o;
        o.x = dv * acc.x + sl * hv.x + bv.x;
        o.y = dv * acc.y + sl * hv.y + bv.y;
        o.z = dv * acc.z + sl * hv.z + bv.z;
        o.w = dv * acc.w + sl * hv.w + bv.w;
        o.x = o.x > 0.f ? o.x : 0.f;
        o.y = o.y > 0.f ? o.y : 0.f;
        o.z = o.z > 0.f ? o.z : 0.f;
        o.w = o.w > 0.f ? o.w : 0.f;
        *(float4*)(hr + (size_t)v * HF + fg * 4) = o;
    }
}

// ---- GEMM2: h2 = hr @ W2  [NN,64]x[64,16] ----------------------------------
__global__ __launch_bounds__(256) void k_gemm2(const float* __restrict__ h,
                                               const float* __restrict__ W2,
                                               float* __restrict__ h2) {
    int j   = threadIdx.x & 15;
    int r   = threadIdx.x >> 4;
    int row = blockIdx.x * 16 + r;
    if (row >= NN) return;
    const float* hrow = h + (size_t)row * HF;
    float acc = 0.f;
    #pragma unroll
    for (int k = 0; k < HF; k += 4) {
        float4 hv = *(const float4*)(hrow + k);
        acc += hv.x * W2[(k + 0) * OF + j];
        acc += hv.y * W2[(k + 1) * OF + j];
        acc += hv.z * W2[(k + 2) * OF + j];
        acc += hv.w * W2[(k + 3) * OF + j];
    }
    h2[(size_t)row * OF + j] = acc;
}

// ---- Gather-aggregate layer 2 (fused self-loop + bias) ---------------------
// one wave per node; 16 edge slots x 4 lanes (float4 = 16 feats)
__global__ __launch_bounds__(256) void k_gather2(const int* __restrict__ rowptr,
                                                 const int* __restrict__ eidx,
                                                 const float* __restrict__ dinv,
                                                 const float* __restrict__ h2,
                                                 const float* __restrict__ b2,
                                                 float* __restrict__ out) {
    int gid   = blockIdx.x * 256 + threadIdx.x;
    int v     = gid >> 6;
    int lane  = threadIdx.x & 63;
    int eslot = lane >> 2;        // 0..15
    int fg    = lane & 3;         // float4 group -> feats 4fg..4fg+3
    int beg = rowptr[v], end = rowptr[v + 1];
    float4 acc = {0.f, 0.f, 0.f, 0.f};
    for (int i = beg + eslot; i < end; i += 16) {
        int s = eidx[i];
        float w = dinv[s];
        float4 hv = *(const float4*)(h2 + (size_t)s * OF + fg * 4);
        acc.x += w * hv.x; acc.y += w * hv.y; acc.z += w * hv.z; acc.w += w * hv.w;
    }
    #pragma unroll
    for (int m = 4; m <= 32; m <<= 1) {
        acc.x += __shfl_xor(acc.x, m);
        acc.y += __shfl_xor(acc.y, m);
        acc.z += __shfl_xor(acc.z, m);
        acc.w += __shfl_xor(acc.w, m);
    }
    if (eslot == 0) {
        float dv = dinv[v];
        float sl = dv * dv;
        float4 hv = *(const float4*)(h2 + (size_t)v * OF + fg * 4);
        float4 bv = *(const float4*)(b2 + fg * 4);
        float4 o;
        o.x = dv * acc.x + sl * hv.x + bv.x;
        o.y = dv * acc.y + sl * hv.y + bv.y;
        o.z = dv * acc.z + sl * hv.z + bv.z;
        o.w = dv * acc.w + sl * hv.w + bv.w;
        *(float4*)(out + (size_t)v * OF + fg * 4) = o;
    }
}

extern "C" void kernel_launch(void* const* d_in, const int* in_sizes, int n_in,
                              void* d_out, int out_size, void* d_ws, size_t ws_size,
                              hipStream_t stream) {
    const float* x   = (const float*)d_in[0];
    const int*   ei  = (const int*)d_in[1];
    const int*   src = ei;            // edge_index[0]
    const int*   dst = ei + NE;       // edge_index[1]
    const float* W1  = (const float*)d_in[2];
    const float* b1  = (const float*)d_in[3];
    const float* W2  = (const float*)d_in[4];
    const float* b2  = (const float*)d_in[5];
    float* out = (float*)d_out;

    // workspace layout (4B units)
    float* dinv   = (float*)d_ws;                       // [100096]
    float* h1     = dinv + 100096;                      // [NN*64]
    float* hr     = h1 + (size_t)NN * HF;               // [NN*64]
    float* h2     = hr + (size_t)NN * HF;               // [NN*16]
    int*   cnt    = (int*)(h2 + (size_t)NN * OF);       // [100096]
    int*   rowptr = cnt + 100096;                       // [100352] (incl. rowptr[NN])
    int*   cursor = rowptr + 100352;                    // [100096]
    int*   eidx   = cursor + 100096;                    // [NE]
    int*   bsum   = eidx + NE;                          // [128]

    hipMemsetAsync(cnt, 0, 100096 * sizeof(int), stream);

    // CSR build + norms
    k_hist<<<(NE + 255) / 256, 256, 0, stream>>>(dst, cnt);
    k_dinv<<<(NN + 255) / 256, 256, 0, stream>>>(cnt, dinv);
    k_reduce<<<NBLK, 256, 0, stream>>>(cnt, bsum);
    k_scan_partials<<<1, 64, 0, stream>>>(bsum);
    k_scan<<<NBLK, 256, 0, stream>>>(cnt, bsum, rowptr, cursor);
    k_scatter<<<(NE + 255) / 256, 256, 0, stream>>>(src, dst, cursor, eidx);

    // layer 1
    k_gemm1<<<(NN + 127) / 128, 256, 0, stream>>>(x, W1, h1);
    k_gather1<<<(NN * HF) / 256, 256, 0, stream>>>(rowptr, eidx, dinv, h1, b1, hr);

    // layer 2
    k_gemm2<<<(NN + 15) / 16, 256, 0, stream>>>(hr, W2, h2);
    k_gather2<<<(NN * HF) / 256, 256, 0, stream>>>(rowptr, eidx, dinv, h2, b2, out);
}

// Round 5
// 251.596 us; speedup vs baseline: 2.4288x; 1.0870x over previous
//
#include <hip/hip_runtime.h>

namespace {
constexpr int NN  = 100000;   // nodes
constexpr int NE  = 1000000;  // edges
constexpr int INF = 256;
constexpr int HF  = 64;
constexpr int OF  = 16;
constexpr int SCAN_CHUNK = 1024;                       // elems per scan block (256 thr x 4)
constexpr int NBLK = (NN + SCAN_CHUNK - 1) / SCAN_CHUNK; // 98
constexpr int NSEG = 8;       // dst segments, pinned to XCDs via blockIdx%8
constexpr int SEGW = (NN + NSEG - 1) / NSEG;             // 12500 nodes / segment
}

typedef __attribute__((ext_vector_type(8))) short     sh8;
typedef __attribute__((ext_vector_type(4))) float     f32x4;
typedef __attribute__((ext_vector_type(4))) unsigned short us4;
typedef __attribute__((ext_vector_type(8))) unsigned short us8;

__device__ __forceinline__ unsigned short f2bf(float f) {
    unsigned int u = __builtin_bit_cast(unsigned int, f);
    u += 0x7FFFu + ((u >> 16) & 1u);       // round-to-nearest-even
    return (unsigned short)(u >> 16);
}

// ---- degree histogram (int) ------------------------------------------------

__global__ void k_hist(const int* __restrict__ dst, int* __restrict__ cnt) {
    int e = blockIdx.x * 256 + threadIdx.x;
    if (e < NE) atomicAdd(&cnt[dst[e]], 1);
}

__global__ void k_dinv(const int* __restrict__ cnt, float* __restrict__ dinv) {
    int v = blockIdx.x * 256 + threadIdx.x;
    if (v < NN) dinv[v] = rsqrtf((float)(cnt[v] + 1));   // +1 self-loop
}

// ---- 2-level exclusive scan of cnt -> rowptr -------------------------------

__global__ __launch_bounds__(256) void k_reduce(const int* __restrict__ cnt,
                                                int* __restrict__ bsum) {
    int t = threadIdx.x;
    int i0 = blockIdx.x * SCAN_CHUNK + t * 4;
    int s = 0;
    #pragma unroll
    for (int q = 0; q < 4; ++q) if (i0 + q < NN) s += cnt[i0 + q];
    #pragma unroll
    for (int off = 32; off > 0; off >>= 1) s += __shfl_down(s, off);
    __shared__ int wsum[4];
    int lane = t & 63, wid = t >> 6;
    if (lane == 0) wsum[wid] = s;
    __syncthreads();
    if (t == 0) bsum[blockIdx.x] = wsum[0] + wsum[1] + wsum[2] + wsum[3];
}

__global__ void k_scan_partials(int* __restrict__ bsum) {
    if (threadIdx.x == 0) {
        int run = 0;
        for (int i = 0; i < NBLK; ++i) { int t = bsum[i]; bsum[i] = run; run += t; }
    }
}

__global__ __launch_bounds__(256) void k_scan(const int* __restrict__ cnt,
                                              const int* __restrict__ bsum,
                                              int* __restrict__ rowptr,
                                              int* __restrict__ cursor) {
    int t = threadIdx.x;
    int i0 = blockIdx.x * SCAN_CHUNK + t * 4;
    int v0 = 0, v1 = 0, v2 = 0, v3 = 0;
    if (i0 + 0 < NN) v0 = cnt[i0 + 0];
    if (i0 + 1 < NN) v1 = cnt[i0 + 1];
    if (i0 + 2 < NN) v2 = cnt[i0 + 2];
    if (i0 + 3 < NN) v3 = cnt[i0 + 3];
    int tsum = v0 + v1 + v2 + v3;
    int lane = t & 63, wid = t >> 6;
    int incl = tsum;
    #pragma unroll
    for (int off = 1; off < 64; off <<= 1) {
        int n = __shfl_up(incl, off);
        if (lane >= off) incl += n;
    }
    __shared__ int wsum[4];
    if (lane == 63) wsum[wid] = incl;
    __syncthreads();
    int woff = 0;
    for (int w = 0; w < wid; ++w) woff += wsum[w];
    int excl = woff + (incl - tsum) + bsum[blockIdx.x];
    int e0 = excl, e1 = e0 + v0, e2 = e1 + v1, e3 = e2 + v2;
    if (i0 + 0 < NN) { rowptr[i0 + 0] = e0; cursor[i0 + 0] = e0; }
    if (i0 + 1 < NN) { rowptr[i0 + 1] = e1; cursor[i0 + 1] = e1; }
    if (i0 + 2 < NN) { rowptr[i0 + 2] = e2; cursor[i0 + 2] = e2; }
    if (i0 + 3 < NN) { rowptr[i0 + 3] = e3; cursor[i0 + 3] = e3; }
    if (i0 + 3 == NN - 1) rowptr[NN] = e3 + v3;
}

// ---- scatter: XCD-pinned dst-segments --------------------------------------
// block b: edge chunk b>>3, dst segment b&7. blockIdx%8 -> XCD (observed
// round-robin), so segment s's cursor slice (50KB) + eidx slice (~500KB)
// stay resident in XCD s's L2: L2-local atomics, full-line write accumulation.
__global__ __launch_bounds__(256) void k_scatter(const int* __restrict__ src,
                                                 const int* __restrict__ dst,
                                                 int* __restrict__ cursor,
                                                 int* __restrict__ eidx) {
    int b     = blockIdx.x;
    int seg   = b & (NSEG - 1);
    int chunk = b >> 3;
    int e = chunk * 256 + threadIdx.x;
    if (e < NE) {
        int d = dst[e];
        if ((unsigned)d / (unsigned)SEGW == (unsigned)seg) {
            int p = atomicAdd(&cursor[d], 1);
            eidx[p] = src[e];
        }
    }
}

// ---- GEMM1: h1 = x @ W1  [NN,256]x[256,64], bf16 MFMA ----------------------
// 128 rows/block, 4 waves; wave w owns rows w*32..w*32+31 (two 16-row M-tiles)
// x full K staged in halves of 128 (fp32 -> bf16 into LDS).
// W1 staged once per block, transposed: wt[col][k] (bf16), so B-frag = 16B
// contiguous along K.  MFMA 16x16x32 bf16: A/B lane&15 = m/n, (lane>>4)*8+j = k;
// D row=(lane>>4)*4+r, col=lane&15 (guide-verified m89/m91).
__global__ __launch_bounds__(256, 2) void k_gemm1(const float* __restrict__ x,
                                                  const float* __restrict__ W1,
                                                  float* __restrict__ h1) {
    __shared__ unsigned short xs[128 * 136];   // stride 136 (272B = 17*16, 2-way banks)
    __shared__ unsigned short wt[64 * 264];    // stride 264 (528B = 33*16, 2-way banks)
    int t = threadIdx.x;
    int w = t >> 6, l = t & 63;
    int row0 = blockIdx.x * 128;

    // stage W1 transposed -> wt[c][k], once per block (W1 is 64KB, L2-hot)
    #pragma unroll
    for (int p = 0; p < 8; ++p) {
        int T   = p * 256 + t;       // 2048 tasks: 64 cols x 32 k-blocks
        int c   = T >> 5;
        int kb8 = T & 31;            // k-block of 8
        const float* wp = W1 + (size_t)(kb8 * 8) * HF + c;
        us8 b;
        #pragma unroll
        for (int j = 0; j < 8; ++j) b[j] = f2bf(wp[j * HF]);
        *(us8*)(wt + c * 264 + kb8 * 8) = b;
    }

    f32x4 acc[2][4];
    #pragma unroll
    for (int i = 0; i < 2; ++i)
        #pragma unroll
        for (int j = 0; j < 4; ++j) acc[i][j] = (f32x4){0.f, 0.f, 0.f, 0.f};

    for (int kb = 0; kb < INF; kb += 128) {
        // stage x tile: 128 rows x 128 cols, fp32 -> bf16
        #pragma unroll
        for (int p = 0; p < 16; ++p) {
            int q    = p * 256 + t;      // 4096 float4 tasks
            int r    = q >> 5;           // row 0..127
            int col4 = q & 31;           // float4 index within the 128-col half
            int gr   = row0 + r; if (gr > NN - 1) gr = NN - 1;
            float4 v = *(const float4*)(x + (size_t)gr * INF + kb + col4 * 4);
            us4 b = { f2bf(v.x), f2bf(v.y), f2bf(v.z), f2bf(v.w) };
            *(us4*)(xs + r * 136 + col4 * 4) = b;
        }
        __syncthreads();   // xs ready (and wt on first iter)
        #pragma unroll
        for (int ks = 0; ks < 4; ++ks) {
            int k0 = ks * 32 + (l >> 4) * 8;      // lane's k within the 128-half
            sh8 a0 = *(const sh8*)(xs + (w * 32 +      (l & 15)) * 136 + k0);
            sh8 a1 = *(const sh8*)(xs + (w * 32 + 16 + (l & 15)) * 136 + k0);
            #pragma unroll
            for (int nt = 0; nt < 4; ++nt) {
                sh8 b = *(const sh8*)(wt + (nt * 16 + (l & 15)) * 264 + kb + k0);
                acc[0][nt] = __builtin_amdgcn_mfma_f32_16x16x32_bf16(a0, b, acc[0][nt], 0, 0, 0);
                acc[1][nt] = __builtin_amdgcn_mfma_f32_16x16x32_bf16(a1, b, acc[1][nt], 0, 0, 0);
            }
        }
        __syncthreads();   // protect xs before next half's staging
    }

    // epilogue: D row=(l>>4)*4+r, col=l&15
    #pragma unroll
    for (int mt = 0; mt < 2; ++mt) {
        #pragma unroll
        for (int r = 0; r < 4; ++r) {
            int gr = row0 + w * 32 + mt * 16 + (l >> 4) * 4 + r;
            if (gr < NN) {
                #pragma unroll
                for (int nt = 0; nt < 4; ++nt)
                    h1[(size_t)gr * HF + nt * 16 + (l & 15)] = acc[mt][nt][r];
            }
        }
    }
}

// ---- Gather-aggregate layer 1 (fused self-loop + bias + relu) --------------
// one wave per node; 4 edge slots x 16 feature groups (float4 each)
__global__ __launch_bounds__(256) void k_gather1(const int* __restrict__ rowptr,
                                                 const int* __restrict__ eidx,
                                                 const float* __restrict__ dinv,
                                                 const float* __restrict__ h1,
                                                 const float* __restrict__ b1,
                                                 float* __restrict__ hr) {
    int gid   = blockIdx.x * 256 + threadIdx.x;
    int v     = gid >> 6;
    int lane  = threadIdx.x & 63;
    int eslot = lane >> 4;        // 0..3
    int fg    = lane & 15;        // float4 group -> feats 4fg..4fg+3
    int beg = rowptr[v], end = rowptr[v + 1];
    float4 acc = {0.f, 0.f, 0.f, 0.f};
    for (int i = beg + eslot; i < end; i += 4) {
        int s = eidx[i];
        float w = dinv[s];
        float4 hv = *(const float4*)(h1 + (size_t)s * HF + fg * 4);
        acc.x += w * hv.x; acc.y += w * hv.y; acc.z += w * hv.z; acc.w += w * hv.w;
    }
    #pragma unroll
    for (int m = 16; m <= 32; m <<= 1) {
        acc.x += __shfl_xor(acc.x, m);
        acc.y += __shfl_xor(acc.y, m);
        acc.z += __shfl_xor(acc.z, m);
        acc.w += __shfl_xor(acc.w, m);
    }
    if (eslot == 0) {
        float dv = dinv[v];
        float sl = dv * dv;
        float4 hv = *(const float4*)(h1 + (size_t)v * HF + fg * 4);
        float4 bv = *(const float4*)(b1 + fg * 4);
        float4 o;
        o.x = dv * acc.x + sl * hv.x + bv.x;
        o.y = dv * acc.y + sl * hv.y + bv.y;
        o.z = dv * acc.z + sl * hv.z + bv.z;
        o.w = dv * acc.w + sl * hv.w + bv.w;
        o.x = o.x > 0.f ? o.x : 0.f;
        o.y = o.y > 0.f ? o.y : 0.f;
        o.z = o.z > 0.f ? o.z : 0.f;
        o.w = o.w > 0.f ? o.w : 0.f;
        *(float4*)(hr + (size_t)v * HF + fg * 4) = o;
    }
}

// ---- GEMM2: h2 = hr @ W2  [NN,64]x[64,16] ----------------------------------
__global__ __launch_bounds__(256) void k_gemm2(const float* __restrict__ h,
                                               const float* __restrict__ W2,
                                               float* __restrict__ h2) {
    int j   = threadIdx.x & 15;
    int r   = threadIdx.x >> 4;
    int row = blockIdx.x * 16 + r;
    if (row >= NN) return;
    const float* hrow = h + (size_t)row * HF;
    float acc = 0.f;
    #pragma unroll
    for (int k = 0; k < HF; k += 4) {
        float4 hv = *(const float4*)(hrow + k);
        acc += hv.x * W2[(k + 0) * OF + j];
        acc += hv.y * W2[(k + 1) * OF + j];
        acc += hv.z * W2[(k + 2) * OF + j];
        acc += hv.w * W2[(k + 3) * OF + j];
    }
    h2[(size_t)row * OF + j] = acc;
}

// ---- Gather-aggregate layer 2 (fused self-loop + bias) ---------------------
// one wave per node; 16 edge slots x 4 lanes (float4 = 16 feats)
__global__ __launch_bounds__(256) void k_gather2(const int* __restrict__ rowptr,
                                                 const int* __restrict__ eidx,
                                                 const float* __restrict__ dinv,
                                                 const float* __restrict__ h2,
                                                 const float* __restrict__ b2,
                                                 float* __restrict__ out) {
    int gid   = blockIdx.x * 256 + threadIdx.x;
    int v     = gid >> 6;
    int lane  = threadIdx.x & 63;
    int eslot = lane >> 2;        // 0..15
    int fg    = lane & 3;         // float4 group -> feats 4fg..4fg+3
    int beg = rowptr[v], end = rowptr[v + 1];
    float4 acc = {0.f, 0.f, 0.f, 0.f};
    for (int i = beg + eslot; i < end; i += 16) {
        int s = eidx[i];
        float w = dinv[s];
        float4 hv = *(const float4*)(h2 + (size_t)s * OF + fg * 4);
        acc.x += w * hv.x; acc.y += w * hv.y; acc.z += w * hv.z; acc.w += w * hv.w;
    }
    #pragma unroll
    for (int m = 4; m <= 32; m <<= 1) {
        acc.x += __shfl_xor(acc.x, m);
        acc.y += __shfl_xor(acc.y, m);
        acc.z += __shfl_xor(acc.z, m);
        acc.w += __shfl_xor(acc.w, m);
    }
    if (eslot == 0) {
        float dv = dinv[v];
        float sl = dv * dv;
        float4 hv = *(const float4*)(h2 + (size_t)v * OF + fg * 4);
        float4 bv = *(const float4*)(b2 + fg * 4);
        float4 o;
        o.x = dv * acc.x + sl * hv.x + bv.x;
        o.y = dv * acc.y + sl * hv.y + bv.y;
        o.z = dv * acc.z + sl * hv.z + bv.z;
        o.w = dv * acc.w + sl * hv.w + bv.w;
        *(float4*)(out + (size_t)v * OF + fg * 4) = o;
    }
}

extern "C" void kernel_launch(void* const* d_in, const int* in_sizes, int n_in,
                              void* d_out, int out_size, void* d_ws, size_t ws_size,
                              hipStream_t stream) {
    const float* x   = (const float*)d_in[0];
    const int*   ei  = (const int*)d_in[1];
    const int*   src = ei;            // edge_index[0]
    const int*   dst = ei + NE;       // edge_index[1]
    const float* W1  = (const float*)d_in[2];
    const float* b1  = (const float*)d_in[3];
    const float* W2  = (const float*)d_in[4];
    const float* b2  = (const float*)d_in[5];
    float* out = (float*)d_out;

    // workspace layout (4B units)
    float* dinv   = (float*)d_ws;                       // [100096]
    float* h1     = dinv + 100096;                      // [NN*64]
    float* hr     = h1 + (size_t)NN * HF;               // [NN*64]
    float* h2     = hr + (size_t)NN * HF;               // [NN*16]
    int*   cnt    = (int*)(h2 + (size_t)NN * OF);       // [100096]
    int*   rowptr = cnt + 100096;                       // [100352] (incl. rowptr[NN])
    int*   cursor = rowptr + 100352;                    // [100096]
    int*   eidx   = cursor + 100096;                    // [NE]
    int*   bsum   = eidx + NE;                          // [128]

    hipMemsetAsync(cnt, 0, 100096 * sizeof(int), stream);

    // CSR build + norms
    k_hist<<<(NE + 255) / 256, 256, 0, stream>>>(dst, cnt);
    k_dinv<<<(NN + 255) / 256, 256, 0, stream>>>(cnt, dinv);
    k_reduce<<<NBLK, 256, 0, stream>>>(cnt, bsum);
    k_scan_partials<<<1, 64, 0, stream>>>(bsum);
    k_scan<<<NBLK, 256, 0, stream>>>(cnt, bsum, rowptr, cursor);
    k_scatter<<<((NE + 255) / 256) * NSEG, 256, 0, stream>>>(src, dst, cursor, eidx);

    // layer 1
    k_gemm1<<<(NN + 127) / 128, 256, 0, stream>>>(x, W1, h1);
    k_gather1<<<(NN * HF) / 256, 256, 0, stream>>>(rowptr, eidx, dinv, h1, b1, hr);

    // layer 2
    k_gemm2<<<(NN + 15) / 16, 256, 0, stream>>>(hr, W2, h2);
    k_gather2<<<(NN * HF) / 256, 256, 0, stream>>>(rowptr, eidx, dinv, h2, b2, out);
}

// Round 6
// 234.348 us; speedup vs baseline: 2.6075x; 1.0736x over previous
//
#include <hip/hip_runtime.h>

namespace {
constexpr int NN  = 100000;   // nodes
constexpr int NE  = 1000000;  // edges
constexpr int INF = 256;
constexpr int HF  = 64;
constexpr int OF  = 16;
constexpr int SCAN_CHUNK = 1024;                       // elems per scan block (256 thr x 4)
constexpr int NBLK = (NN + SCAN_CHUNK - 1) / SCAN_CHUNK; // 98
constexpr int NSEG = 8;       // dst segments, pinned to XCDs via blockIdx%8
constexpr int SEGW = (NN + NSEG - 1) / NSEG;             // 12500 nodes / segment
}

typedef __attribute__((ext_vector_type(8))) short     sh8;
typedef __attribute__((ext_vector_type(4))) float     f32x4;
typedef __attribute__((ext_vector_type(8))) unsigned short us8;

__device__ __forceinline__ unsigned short f2bf(float f) {
    unsigned int u = __builtin_bit_cast(unsigned int, f);
    u += 0x7FFFu + ((u >> 16) & 1u);       // round-to-nearest-even
    return (unsigned short)(u >> 16);
}

// ---- degree histogram (int), XCD-pinned dst segments -----------------------

__global__ void k_hist(const int* __restrict__ dst, int* __restrict__ cnt) {
    int b     = blockIdx.x;
    int seg   = b & (NSEG - 1);
    int chunk = b >> 3;
    int e = chunk * 256 + threadIdx.x;
    if (e < NE) {
        int d = dst[e];
        if ((unsigned)d / (unsigned)SEGW == (unsigned)seg)
            atomicAdd(&cnt[d], 1);
    }
}

__global__ void k_dinv(const int* __restrict__ cnt, float* __restrict__ dinv) {
    int v = blockIdx.x * 256 + threadIdx.x;
    if (v < NN) dinv[v] = rsqrtf((float)(cnt[v] + 1));   // +1 self-loop
}

// ---- W1 -> bf16 transposed (wt_g[c*256+k] = bf16(W1[k*64+c])), once --------
__global__ void k_wconv(const float* __restrict__ W1, unsigned short* __restrict__ wt_g) {
    int idx = blockIdx.x * 256 + threadIdx.x;   // 16384 tasks
    int c = idx >> 8, k = idx & 255;
    wt_g[idx] = f2bf(W1[(size_t)k * HF + c]);
}

// ---- 2-level exclusive scan of cnt -> rowptr -------------------------------

__global__ __launch_bounds__(256) void k_reduce(const int* __restrict__ cnt,
                                                int* __restrict__ bsum) {
    int t = threadIdx.x;
    int i0 = blockIdx.x * SCAN_CHUNK + t * 4;
    int s = 0;
    #pragma unroll
    for (int q = 0; q < 4; ++q) if (i0 + q < NN) s += cnt[i0 + q];
    #pragma unroll
    for (int off = 32; off > 0; off >>= 1) s += __shfl_down(s, off);
    __shared__ int wsum[4];
    int lane = t & 63, wid = t >> 6;
    if (lane == 0) wsum[wid] = s;
    __syncthreads();
    if (t == 0) bsum[blockIdx.x] = wsum[0] + wsum[1] + wsum[2] + wsum[3];
}

__global__ void k_scan_partials(int* __restrict__ bsum) {
    if (threadIdx.x == 0) {
        int run = 0;
        for (int i = 0; i < NBLK; ++i) { int t = bsum[i]; bsum[i] = run; run += t; }
    }
}

__global__ __launch_bounds__(256) void k_scan(const int* __restrict__ cnt,
                                              const int* __restrict__ bsum,
                                              int* __restrict__ rowptr,
                                              int* __restrict__ cursor) {
    int t = threadIdx.x;
    int i0 = blockIdx.x * SCAN_CHUNK + t * 4;
    int v0 = 0, v1 = 0, v2 = 0, v3 = 0;
    if (i0 + 0 < NN) v0 = cnt[i0 + 0];
    if (i0 + 1 < NN) v1 = cnt[i0 + 1];
    if (i0 + 2 < NN) v2 = cnt[i0 + 2];
    if (i0 + 3 < NN) v3 = cnt[i0 + 3];
    int tsum = v0 + v1 + v2 + v3;
    int lane = t & 63, wid = t >> 6;
    int incl = tsum;
    #pragma unroll
    for (int off = 1; off < 64; off <<= 1) {
        int n = __shfl_up(incl, off);
        if (lane >= off) incl += n;
    }
    __shared__ int wsum[4];
    if (lane == 63) wsum[wid] = incl;
    __syncthreads();
    int woff = 0;
    for (int w = 0; w < wid; ++w) woff += wsum[w];
    int excl = woff + (incl - tsum) + bsum[blockIdx.x];
    int e0 = excl, e1 = e0 + v0, e2 = e1 + v1, e3 = e2 + v2;
    if (i0 + 0 < NN) { rowptr[i0 + 0] = e0; cursor[i0 + 0] = e0; }
    if (i0 + 1 < NN) { rowptr[i0 + 1] = e1; cursor[i0 + 1] = e1; }
    if (i0 + 2 < NN) { rowptr[i0 + 2] = e2; cursor[i0 + 2] = e2; }
    if (i0 + 3 < NN) { rowptr[i0 + 3] = e3; cursor[i0 + 3] = e3; }
    if (i0 + 3 == NN - 1) rowptr[NN] = e3 + v3;
}

// ---- scatter: XCD-pinned dst-segments --------------------------------------
__global__ __launch_bounds__(256) void k_scatter(const int* __restrict__ src,
                                                 const int* __restrict__ dst,
                                                 int* __restrict__ cursor,
                                                 int* __restrict__ eidx) {
    int b     = blockIdx.x;
    int seg   = b & (NSEG - 1);
    int chunk = b >> 3;
    int e = chunk * 256 + threadIdx.x;
    if (e < NE) {
        int d = dst[e];
        if ((unsigned)d / (unsigned)SEGW == (unsigned)seg) {
            int p = atomicAdd(&cursor[d], 1);
            eidx[p] = src[e];
        }
    }
}

// ---- GEMM1: h1 = x @ W1  [NN,256]x[256,64], bf16 MFMA ----------------------
// 128 rows/block, 4 waves, wave w owns rows w*32..w*32+31 (two 16-row M-tiles).
// A-fragments load DIRECTLY from global x (lane l&15 = row, (l>>4)*8 = k base;
// 4-lane groups form contiguous 128B segments) with in-register fp32->bf16.
// W staged once per block from pre-transposed bf16 wt_g (coalesced 16B loads).
// No per-K barriers; LDS 33.8KB -> 4 blocks/CU.
__global__ __launch_bounds__(256, 4) void k_gemm1(const float* __restrict__ x,
                                                  const unsigned short* __restrict__ wt_g,
                                                  float* __restrict__ h1) {
    __shared__ unsigned short wt[64 * 264];    // stride 264 (528B): rows r,r+8 share bank = 2-way (free)
    int t = threadIdx.x;
    int w = t >> 6, l = t & 63;
    int row0 = blockIdx.x * 128;

    #pragma unroll
    for (int p = 0; p < 8; ++p) {
        int T   = p * 256 + t;       // 2048 tasks: 64 rows x 32 chunks of 8 bf16
        int c   = T >> 5;
        int kb8 = T & 31;
        *(us8*)(wt + c * 264 + kb8 * 8) = *(const us8*)(wt_g + c * 256 + kb8 * 8);
    }
    __syncthreads();

    int m = l & 15;          // row within M-tile
    int g = l >> 4;          // k-group (0..3) -> k offset g*8
    int gr0 = row0 + w * 32 + m;      if (gr0 > NN - 1) gr0 = NN - 1;
    int gr1 = row0 + w * 32 + 16 + m; if (gr1 > NN - 1) gr1 = NN - 1;
    const float* p0 = x + (size_t)gr0 * INF + g * 8;
    const float* p1 = x + (size_t)gr1 * INF + g * 8;

    f32x4 acc[2][4];
    #pragma unroll
    for (int i = 0; i < 2; ++i)
        #pragma unroll
        for (int j = 0; j < 4; ++j) acc[i][j] = (f32x4){0.f, 0.f, 0.f, 0.f};

    #pragma unroll 2
    for (int kb = 0; kb < INF; kb += 32) {
        float4 u0 = *(const float4*)(p0 + kb);
        float4 u1 = *(const float4*)(p0 + kb + 4);
        float4 u2 = *(const float4*)(p1 + kb);
        float4 u3 = *(const float4*)(p1 + kb + 4);
        us8 a0u = { f2bf(u0.x), f2bf(u0.y), f2bf(u0.z), f2bf(u0.w),
                    f2bf(u1.x), f2bf(u1.y), f2bf(u1.z), f2bf(u1.w) };
        us8 a1u = { f2bf(u2.x), f2bf(u2.y), f2bf(u2.z), f2bf(u2.w),
                    f2bf(u3.x), f2bf(u3.y), f2bf(u3.z), f2bf(u3.w) };
        sh8 a0 = __builtin_bit_cast(sh8, a0u);
        sh8 a1 = __builtin_bit_cast(sh8, a1u);
        #pragma unroll
        for (int nt = 0; nt < 4; ++nt) {
            sh8 b = *(const sh8*)(wt + (nt * 16 + m) * 264 + kb + g * 8);
            acc[0][nt] = __builtin_amdgcn_mfma_f32_16x16x32_bf16(a0, b, acc[0][nt], 0, 0, 0);
            acc[1][nt] = __builtin_amdgcn_mfma_f32_16x16x32_bf16(a1, b, acc[1][nt], 0, 0, 0);
        }
    }

    // epilogue: D row=(l>>4)*4+r, col=l&15
    #pragma unroll
    for (int mt = 0; mt < 2; ++mt) {
        #pragma unroll
        for (int r = 0; r < 4; ++r) {
            int gr = row0 + w * 32 + mt * 16 + (l >> 4) * 4 + r;
            if (gr < NN) {
                #pragma unroll
                for (int nt = 0; nt < 4; ++nt)
                    h1[(size_t)gr * HF + nt * 16 + (l & 15)] = acc[mt][nt][r];
            }
        }
    }
}

// ---- Gather-aggregate layer 1 (fused self-loop + bias + relu) --------------
// one wave per node; 4 edge slots x 16 feature groups (float4 each)
__global__ __launch_bounds__(256) void k_gather1(const int* __restrict__ rowptr,
                                                 const int* __restrict__ eidx,
                                                 const float* __restrict__ dinv,
                                                 const float* __restrict__ h1,
                                                 const float* __restrict__ b1,
                                                 float* __restrict__ hr) {
    int gid   = blockIdx.x * 256 + threadIdx.x;
    int v     = gid >> 6;
    int lane  = threadIdx.x & 63;
    int eslot = lane >> 4;        // 0..3
    int fg    = lane & 15;        // float4 group -> feats 4fg..4fg+3
    int beg = rowptr[v], end = rowptr[v + 1];
    float4 acc = {0.f, 0.f, 0.f, 0.f};
    for (int i = beg + eslot; i < end; i += 4) {
        int s = eidx[i];
        float w = dinv[s];
        float4 hv = *(const float4*)(h1 + (size_t)s * HF + fg * 4);
        acc.x += w * hv.x; acc.y += w * hv.y; acc.z += w * hv.z; acc.w += w * hv.w;
    }
    #pragma unroll
    for (int m = 16; m <= 32; m <<= 1) {
        acc.x += __shfl_xor(acc.x, m);
        acc.y += __shfl_xor(acc.y, m);
        acc.z += __shfl_xor(acc.z, m);
        acc.w += __shfl_xor(acc.w, m);
    }
    if (eslot == 0) {
        float dv = dinv[v];
        float sl = dv * dv;
        float4 hv = *(const float4*)(h1 + (size_t)v * HF + fg * 4);
        float4 bv = *(const float4*)(b1 + fg * 4);
        float4 o;
        o.x = dv * acc.x + sl * hv.x + bv.x;
        o.y = dv * acc.y + sl * hv.y + bv.y;
        o.z = dv * acc.z + sl * hv.z + bv.z;
        o.w = dv * acc.w + sl * hv.w + bv.w;
        o.x = o.x > 0.f ? o.x : 0.f;
        o.y = o.y > 0.f ? o.y : 0.f;
        o.z = o.z > 0.f ? o.z : 0.f;
        o.w = o.w > 0.f ? o.w : 0.f;
        *(float4*)(hr + (size_t)v * HF + fg * 4) = o;
    }
}

// ---- GEMM2: h2 = hr @ W2  [NN,64]x[64,16] ----------------------------------
__global__ __launch_bounds__(256) void k_gemm2(const float* __restrict__ h,
                                               const float* __restrict__ W2,
                                               float* __restrict__ h2) {
    int j   = threadIdx.x & 15;
    int r   = threadIdx.x >> 4;
    int row = blockIdx.x * 16 + r;
    if (row >= NN) return;
    const float* hrow = h + (size_t)row * HF;
    float acc = 0.f;
    #pragma unroll
    for (int k = 0; k < HF; k += 4) {
        float4 hv = *(const float4*)(hrow + k);
        acc += hv.x * W2[(k + 0) * OF + j];
        acc += hv.y * W2[(k + 1) * OF + j];
        acc += hv.z * W2[(k + 2) * OF + j];
        acc += hv.w * W2[(k + 3) * OF + j];
    }
    h2[(size_t)row * OF + j] = acc;
}

// ---- Gather-aggregate layer 2 (fused self-loop + bias) ---------------------
// one wave per node; 16 edge slots x 4 lanes (float4 = 16 feats)
__global__ __launch_bounds__(256) void k_gather2(const int* __restrict__ rowptr,
                                                 const int* __restrict__ eidx,
                                                 const float* __restrict__ dinv,
                                                 const float* __restrict__ h2,
                                                 const float* __restrict__ b2,
                                                 float* __restrict__ out) {
    int gid   = blockIdx.x * 256 + threadIdx.x;
    int v     = gid >> 6;
    int lane  = threadIdx.x & 63;
    int eslot = lane >> 2;        // 0..15
    int fg    = lane & 3;         // float4 group -> feats 4fg..4fg+3
    int beg = rowptr[v], end = rowptr[v + 1];
    float4 acc = {0.f, 0.f, 0.f, 0.f};
    for (int i = beg + eslot; i < end; i += 16) {
        int s = eidx[i];
        float w = dinv[s];
        float4 hv = *(const float4*)(h2 + (size_t)s * OF + fg * 4);
        acc.x += w * hv.x; acc.y += w * hv.y; acc.z += w * hv.z; acc.w += w * hv.w;
    }
    #pragma unroll
    for (int m = 4; m <= 32; m <<= 1) {
        acc.x += __shfl_xor(acc.x, m);
        acc.y += __shfl_xor(acc.y, m);
        acc.z += __shfl_xor(acc.z, m);
        acc.w += __shfl_xor(acc.w, m);
    }
    if (eslot == 0) {
        float dv = dinv[v];
        float sl = dv * dv;
        float4 hv = *(const float4*)(h2 + (size_t)v * OF + fg * 4);
        float4 bv = *(const float4*)(b2 + fg * 4);
        float4 o;
        o.x = dv * acc.x + sl * hv.x + bv.x;
        o.y = dv * acc.y + sl * hv.y + bv.y;
        o.z = dv * acc.z + sl * hv.z + bv.z;
        o.w = dv * acc.w + sl * hv.w + bv.w;
        *(float4*)(out + (size_t)v * OF + fg * 4) = o;
    }
}

extern "C" void kernel_launch(void* const* d_in, const int* in_sizes, int n_in,
                              void* d_out, int out_size, void* d_ws, size_t ws_size,
                              hipStream_t stream) {
    const float* x   = (const float*)d_in[0];
    const int*   ei  = (const int*)d_in[1];
    const int*   src = ei;            // edge_index[0]
    const int*   dst = ei + NE;       // edge_index[1]
    const float* W1  = (const float*)d_in[2];
    const float* b1  = (const float*)d_in[3];
    const float* W2  = (const float*)d_in[4];
    const float* b2  = (const float*)d_in[5];
    float* out = (float*)d_out;

    // workspace layout (4B units)
    float* dinv   = (float*)d_ws;                       // [100096]
    float* h1     = dinv + 100096;                      // [NN*64]
    float* hr     = h1 + (size_t)NN * HF;               // [NN*64]
    float* h2     = hr + (size_t)NN * HF;               // [NN*16]
    int*   cnt    = (int*)(h2 + (size_t)NN * OF);       // [100096]
    int*   rowptr = cnt + 100096;                       // [100352] (incl. rowptr[NN])
    int*   cursor = rowptr + 100352;                    // [100096]
    int*   eidx   = cursor + 100096;                    // [NE]
    int*   bsum   = eidx + NE;                          // [128]
    unsigned short* wt_g = (unsigned short*)(bsum + 128);  // [64*256] bf16

    hipMemsetAsync(cnt, 0, 100096 * sizeof(int), stream);

    // CSR build + norms + W pre-transpose
    k_hist<<<((NE + 255) / 256) * NSEG, 256, 0, stream>>>(dst, cnt);
    k_wconv<<<64, 256, 0, stream>>>(W1, wt_g);
    k_dinv<<<(NN + 255) / 256, 256, 0, stream>>>(cnt, dinv);
    k_reduce<<<NBLK, 256, 0, stream>>>(cnt, bsum);
    k_scan_partials<<<1, 64, 0, stream>>>(bsum);
    k_scan<<<NBLK, 256, 0, stream>>>(cnt, bsum, rowptr, cursor);
    k_scatter<<<((NE + 255) / 256) * NSEG, 256, 0, stream>>>(src, dst, cursor, eidx);

    // layer 1
    k_gemm1<<<(NN + 127) / 128, 256, 0, stream>>>(x, wt_g, h1);
    k_gather1<<<(NN * HF) / 256, 256, 0, stream>>>(rowptr, eidx, dinv, h1, b1, hr);

    // layer 2
    k_gemm2<<<(NN + 15) / 16, 256, 0, stream>>>(hr, W2, h2);
    k_gather2<<<(NN * HF) / 256, 256, 0, stream>>>(rowptr, eidx, dinv, h2, b2, out);
}